// Round 22
// baseline (68.904 us; speedup 1.0000x reference)
//
#include <hip/hip_runtime.h>
#include <hip/hip_bf16.h>

#define CIN  64
#define HH   128
#define WW   128
#define COUT 128
#define HO   126
#define WO   126
#define NB   32
#define HW   (HH * WW)

typedef __bf16 bf16x8 __attribute__((ext_vector_type(8)));
typedef float f32x4 __attribute__((ext_vector_type(4)));

// ws2 granule layout: [step(18)=(s,h)][kg(4)][cout(128)] 16B granules
// granule(step,kg,cout)[j] = bf16(w[cout][ci = 32h + 8kg + j][s])
__global__ void wreorder_3556(const float* __restrict__ w, unsigned short* __restrict__ ws2) {
    int e = blockIdx.x * 256 + threadIdx.x;      // 0..73727
    if (e >= 73728) return;
    int j = e & 7, cout = (e >> 3) & 127, kg = (e >> 10) & 3, h = (e >> 12) & 1, s = e >> 13;
    __bf16 v = (__bf16)w[cout * 576 + (h * 32 + kg * 8 + j) * 9 + s];
    ws2[e] = __builtin_bit_cast(unsigned short, v);
}

// LDS x layout: [row(4)][h(2)][colblk(9)][kg(4)][c(16)] 16B granules, block stride 1040B
#define ROW_STRIDE 18720
#define H_STRIDE   9360
#define BLK_STRIDE 1040
#define PM_OFF  74880
#define SMEM_BYTES (74880 + 2048)   // 76928 -> 2 blocks/CU

__device__ __forceinline__ unsigned lds_addr(const void* p) {
    return (unsigned)(unsigned long long)(const __attribute__((address_space(3))) unsigned char*)p;
}
template<int OFF>
__device__ __forceinline__ bf16x8 ds_read128(unsigned base) {
    bf16x8 d;
    asm volatile("ds_read_b128 %0, %1 offset:%c2" : "=v"(d) : "v"(base), "i"(OFF));
    return d;
}
template<int OFF>
__device__ __forceinline__ bf16x8 glob_load128(const unsigned char* sbase, unsigned voff) {
    bf16x8 d;
    asm volatile("global_load_dwordx4 %0, %1, %2 offset:%c3"
                 : "=v"(d) : "v"(voff), "s"(sbase), "i"(OFF));
    return d;
}

#define MFMA16_(a, b, c) __builtin_amdgcn_mfma_f32_16x16x32_bf16((a), (b), (c), 0, 0, 0)
#define SBAR() __builtin_amdgcn_sched_barrier(0)

// slice S: kh = S/3, kw = S%3
#define KH2_(S) ((S) / 3)
#define KW2_(S) ((S) % 3)
#define IMB2(S, H, N) (KH2_(S) * ROW_STRIDE + (H) * H_STRIDE + (N) * BLK_STRIDE)

template<bool USE_WS>
__global__ __launch_bounds__(256, 2)
void conv_min_tanh_3556(const float* __restrict__ x, const float* __restrict__ w,
                        const float* __restrict__ bias,
                        const unsigned char* __restrict__ wsr_b,
                        float* __restrict__ out) {
    __shared__ __align__(16) unsigned char smem[SMEM_BYTES];
    float* pmin = (float*)(smem + PM_OFF);

    // XCD-chunked bijective swizzle (2016 = 8 * 252)
    const int bid = blockIdx.x;
    const int blk = (bid & 7) * 252 + (bid >> 3);
    const int b   = blk / 63;
    const int R   = (blk - b * 63) * 2;      // output rows R, R+1; input rows R..R+3

    const int tid  = threadIdx.x;
    const int lane = tid & 63;
    const int wid  = tid >> 6;               // 0..3
    const int l15 = lane & 15;
    const int lg  = lane >> 4;               // 0..3 (16-lane group)
    const int waveM = wid & 1;               // cout half (0/1)
    const int waveR = wid >> 1;              // output row within pair (0/1)
    const int mb = waveM * 64;

    // ---- single-buffered operand registers
    bf16x8 Af[2][4];   // [h][m]  32 VGPR
    bf16x8 Bf[2][8];   // [h][n]  64 VGPR
    const unsigned voffA = (unsigned)(lg * 2048 + (mb + l15) * 16);

    #define RELA_H(S1, H) do { const unsigned _va = voffA + (2u*(S1)+(H)) * 8192u;        \
        Af[H][0] = glob_load128<0>(wsr_b, _va);                                           \
        Af[H][1] = glob_load128<256>(wsr_b, _va);                                         \
        Af[H][2] = glob_load128<512>(wsr_b, _va);                                         \
        Af[H][3] = glob_load128<768>(wsr_b, _va); } while (0)

    if constexpr (USE_WS) { RELA_H(0, 0); RELA_H(0, 1); }   // hidden under staging

    // ---- stage x rows R..R+3, vectorized f32x4 loads, block-16-col layout
    {
        const float* xb = x + (size_t)b * CIN * HW + (size_t)R * WW;
        #pragma unroll
        for (int it = 0; it < 4; ++it) {
            int item = it * 256 + tid;          // 0..1023
            int col4 = item & 31;
            int cg   = (item >> 5) & 7;         // h = cg>>2, kg = cg&3
            int row  = item >> 8;               // 0..3
            const float* src = xb + (size_t)(cg * 8) * HW + (size_t)row * WW + col4 * 4;
            f32x4 v[8];
            #pragma unroll
            for (int j = 0; j < 8; ++j) v[j] = *(const f32x4*)(src + (size_t)j * HW);
            const int wb0 = row * ROW_STRIDE + (cg >> 2) * H_STRIDE + (cg & 3) * 256;
            #pragma unroll
            for (int c = 0; c < 4; ++c) {
                int col = col4 * 4 + c;
                union { unsigned short us[8]; int4 i4; } p;
                #pragma unroll
                for (int j = 0; j < 8; ++j) {
                    __bf16 t = (__bf16)v[j][c];
                    p.us[j] = __builtin_bit_cast(unsigned short, t);
                }
                *(int4*)(smem + wb0 + (col >> 4) * BLK_STRIDE + (col & 15) * 16) = p.i4;
            }
        }
        if (tid < 64) {   // zero-pad block 8 (cols 128,129)
            int row = tid >> 4, hh = (tid >> 3) & 1, kg = (tid >> 1) & 3, cz = tid & 1;
            int4 z = {0, 0, 0, 0};
            *(int4*)(smem + row * ROW_STRIDE + hh * H_STRIDE + 8 * BLK_STRIDE + kg * 256 + cz * 16) = z;
        }
    }
    __syncthreads();   // drains vm+lgkm: Af[s0] resident, xs ready

    f32x4 acc[4][8] = {};   // [m][n] : 64 cout x 128 col, 16x16 tiles

    if constexpr (USE_WS) {
        unsigned baseB[3];
        #pragma unroll
        for (int kw = 0; kw < 3; ++kw) {
            int cp = l15 + kw;
            baseB[kw] = lds_addr(smem) + (unsigned)(waveR * ROW_STRIDE + lg * 256 +
                        (cp >> 4) * BLK_STRIDE + (cp & 15) * 16);
        }

        #define RELB(S1, NP, H) do { const unsigned _bb = baseB[KW2_(S1)];                \
            Bf[H][2*(NP)]   = ds_read128<IMB2(S1, H, 2*(NP))>(_bb);                       \
            Bf[H][2*(NP)+1] = ds_read128<IMB2(S1, H, 2*(NP)+1)>(_bb); } while (0)

        #define GRP_BODY(NP, H) do {                                                      \
            __builtin_amdgcn_s_setprio(1);                                                \
            _Pragma("unroll")                                                             \
            for (int _m = 0; _m < 4; ++_m) {                                              \
                acc[_m][2*(NP)]   = MFMA16_(Af[H][_m], Bf[H][2*(NP)],   acc[_m][2*(NP)]); \
                acc[_m][2*(NP)+1] = MFMA16_(Af[H][_m], Bf[H][2*(NP)+1], acc[_m][2*(NP)+1]); \
            }                                                                             \
            __builtin_amdgcn_s_setprio(0);                                                \
        } while (0)

        #define WAITLV(LGK, VMC) do {                                                     \
            asm volatile("s_waitcnt lgkmcnt(" #LGK ") vmcnt(" #VMC ")" ::: "memory");     \
            SBAR(); } while (0)
        #define WAITL(LGK) do {                                                           \
            asm volatile("s_waitcnt lgkmcnt(" #LGK ")" ::: "memory");                     \
            SBAR(); } while (0)

        // Counts (in-order retire): B-pair for (g,S) issued at group g of S-1; at most 14
        // newer ds ops exist at its wait -> lgkmcnt(14). A[h] issued at S-1 g6/g7 -> vm(4)/vm(0)
        // at groups 0/1 only. Final step: 14-2g (no step-8 reloads).
        #define KSTEP(S) do {                                                             \
            WAITLV(14, 4); GRP_BODY(0, 0); SBAR(); RELB((S)+1, 0, 0); SBAR();             \
            WAITLV(14, 0); GRP_BODY(0, 1); SBAR(); RELB((S)+1, 0, 1); SBAR();             \
            WAITL(14);     GRP_BODY(1, 0); SBAR(); RELB((S)+1, 1, 0); SBAR();             \
            WAITL(14);     GRP_BODY(1, 1); SBAR(); RELB((S)+1, 1, 1); SBAR();             \
            WAITL(14);     GRP_BODY(2, 0); SBAR(); RELB((S)+1, 2, 0); SBAR();             \
            WAITL(14);     GRP_BODY(2, 1); SBAR(); RELB((S)+1, 2, 1); SBAR();             \
            WAITL(14);     GRP_BODY(3, 0); SBAR(); RELB((S)+1, 3, 0); RELA_H((S)+1, 0); SBAR(); \
            WAITL(14);     GRP_BODY(3, 1); SBAR(); RELB((S)+1, 3, 1); RELA_H((S)+1, 1); SBAR(); \
        } while (0)

        #define KSTEP8() do {                                                             \
            WAITLV(14, 4); GRP_BODY(0, 0); SBAR();                                        \
            WAITLV(12, 0); GRP_BODY(0, 1); SBAR();                                        \
            WAITL(10);     GRP_BODY(1, 0); SBAR();                                        \
            WAITL(8);      GRP_BODY(1, 1); SBAR();                                        \
            WAITL(6);      GRP_BODY(2, 0); SBAR();                                        \
            WAITL(4);      GRP_BODY(2, 1); SBAR();                                        \
            WAITL(2);      GRP_BODY(3, 0); SBAR();                                        \
            WAITL(0);      GRP_BODY(3, 1); SBAR();                                        \
        } while (0)

        // B prologue for step 0 in consumption (oldest-first) order
        RELB(0, 0, 0); RELB(0, 0, 1); RELB(0, 1, 0); RELB(0, 1, 1);
        RELB(0, 2, 0); RELB(0, 2, 1); RELB(0, 3, 0); RELB(0, 3, 1);

        KSTEP(0); KSTEP(1); KSTEP(2); KSTEP(3); KSTEP(4);
        KSTEP(5); KSTEP(6); KSTEP(7); KSTEP8();

        asm volatile("s_waitcnt lgkmcnt(0) vmcnt(0)" ::: "memory");
        SBAR();
    } else {
        // fallback: plain 18-step loop straight from w
        #pragma unroll
        for (int step = 0; step < 18; ++step) {
            const int s = step >> 1, h = step & 1;
            const int kh = s / 3, kw = s % 3;
            bf16x8 A[4], B[8];
            #pragma unroll
            for (int m = 0; m < 4; ++m)
                #pragma unroll
                for (int j = 0; j < 8; ++j)
                    A[m][j] = (__bf16)w[(mb + m * 16 + l15) * 576 +
                                        (h * 32 + lg * 8 + j) * 9 + s];
            #pragma unroll
            for (int n = 0; n < 8; ++n) {
                int col = n * 16 + l15 + kw;
                B[n] = *(const bf16x8*)(smem + (waveR + kh) * ROW_STRIDE + h * H_STRIDE +
                                        (col >> 4) * BLK_STRIDE + lg * 256 + (col & 15) * 16);
            }
            #pragma unroll
            for (int m = 0; m < 4; ++m)
                #pragma unroll
                for (int n = 0; n < 8; ++n)
                    acc[m][n] = MFMA16_(A[m], B[n], acc[m][n]);
        }
    }

    // ---- epilogue: +bias, min over this wave's 64 couts, shfl, cross-waveM via pmin
    {
        float pm[8];
        #pragma unroll
        for (int n = 0; n < 8; ++n) pm[n] = 1e30f;
        #pragma unroll
        for (int m = 0; m < 4; ++m) {
            #pragma unroll
            for (int r = 0; r < 4; ++r) {
                float bv = bias[mb + m * 16 + lg * 4 + r];
                #pragma unroll
                for (int n = 0; n < 8; ++n)
                    pm[n] = fminf(pm[n], acc[m][n][r] + bv);
            }
        }
        #pragma unroll
        for (int n = 0; n < 8; ++n) {
            pm[n] = fminf(pm[n], __shfl_xor(pm[n], 16, 64));
            pm[n] = fminf(pm[n], __shfl_xor(pm[n], 32, 64));
        }
        if (lg == 0) {
            #pragma unroll
            for (int n = 0; n < 8; ++n)
                pmin[(waveR * 2 + waveM) * 128 + n * 16 + l15] = pm[n];
        }
    }
    __syncthreads();
    {
        const int hh  = tid >> 7;            // 0..1
        const int col = tid & 127;
        if (col < WO) {
            float v = fminf(pmin[(hh * 2 + 0) * 128 + col], pmin[(hh * 2 + 1) * 128 + col]);
            v = tanhf(tanhf(v));
            out[((size_t)b * HO + R + hh) * WO + col] = v;
        }
    }
}

extern "C" void kernel_launch(void* const* d_in, const int* in_sizes, int n_in,
                              void* d_out, int out_size, void* d_ws, size_t ws_size,
                              hipStream_t stream) {
    const float* x    = (const float*)d_in[0];
    const float* w    = (const float*)d_in[1];
    const float* bias = (const float*)d_in[2];
    float* out = (float*)d_out;

    const size_t ws_needed = (size_t)18 * 4 * 128 * 16;   // 147456 B
    if (ws_size >= ws_needed) {
        unsigned short* wsb = (unsigned short*)d_ws;
        wreorder_3556<<<288, 256, 0, stream>>>(w, wsb);
        conv_min_tanh_3556<true><<<NB * 63, 256, 0, stream>>>(x, w, bias, (const unsigned char*)wsb, out);
    } else {
        conv_min_tanh_3556<false><<<NB * 63, 256, 0, stream>>>(x, w, bias, nullptr, out);
    }
}